// Round 8
// baseline (61.501 us; speedup 1.0000x reference)
//
#include <hip/hip_runtime.h>

#define P   7
#define GS  7
#define D   21
#define HH  80
#define WW  80
#define CC  (D * GS * GS)        // 1029
#define PLANE (HH * WW)          // 6400 floats
#define IW  84                   // gll-compatible stride (16B-divisible rows)
#define NCHUNK (HH * (IW / 4))   // 80 rows * 21 chunks = 1680
#define NSEG 5
#define SEGLEN 16

// fl32(1/7) = 0x3E124925 — the golden divides via reciprocal multiply.
__device__ __forceinline__ float recip7() {
    union { unsigned u; float f; } c; c.u = 0x3E124925u; return c.f;
}

// a*b + c with a HARD barrier between mul and add: no fma contraction ever.
__device__ __forceinline__ float mul_add_nofma(float a, float b, float c) {
    float t = a * b;
    asm volatile("" : "+v"(t));
    return t + c;
}

__device__ __forceinline__ void gll16(const float* g, float* l) {
    __builtin_amdgcn_global_load_lds(
        (const __attribute__((address_space(1))) void*)g,
        (__attribute__((address_space(3))) void*)l,
        16, 0, 0);
}

// ---------- edge kernel: per-(roi, gh, gw) packed edges + 1/area ------------
__global__ __launch_bounds__(256) void edge_kernel(
    const float* __restrict__ rois, int R, uint2* __restrict__ tab)
{
    int r = blockIdx.x * 256 + threadIdx.x;
    if (r >= R) return;
    const float* roi = rois + (size_t)r * 5;

    float x1 = rintf(roi[1]) * 0.0625f;
    float y1 = rintf(roi[2]) * 0.0625f;
    float x2 = (rintf(roi[3]) + 1.0f) * 0.0625f;
    float y2 = (rintf(roi[4]) + 1.0f) * 0.0625f;
    float bin_w = fmaxf(x2 - x1, 0.1f) * recip7();
    float bin_h = fmaxf(y2 - y1, 0.1f) * recip7();
    asm volatile("" : "+v"(bin_w), "+v"(bin_h));

    int hsA[7], heA[7], wsA[7], weA[7];
    #pragma unroll
    for (int g = 0; g < 7; ++g) {
        float hs_f = floorf(mul_add_nofma((float)g,       bin_h, y1));
        float he_f = ceilf (mul_add_nofma((float)(g + 1), bin_h, y1));
        float ws_f = floorf(mul_add_nofma((float)g,       bin_w, x1));
        float we_f = ceilf (mul_add_nofma((float)(g + 1), bin_w, x1));
        hsA[g] = (int)fminf(fmaxf(hs_f, 0.0f), 80.0f);
        heA[g] = (int)fminf(fmaxf(he_f, 0.0f), 80.0f);
        wsA[g] = (int)fminf(fmaxf(ws_f, 0.0f), 80.0f);
        weA[g] = (int)fminf(fmaxf(we_f, 0.0f), 80.0f);
    }
    uint2* t = tab + (size_t)r * 49;
    #pragma unroll
    for (int gh = 0; gh < 7; ++gh) {
        #pragma unroll
        for (int gw = 0; gw < 7; ++gw) {
            int hs = hsA[gh], he = heA[gh], ws = wsA[gw], we = weA[gw];
            int area = (he - hs) * (we - ws);
            float rcp = (area > 0) ? (1.0f / (float)area) : 0.0f;
            unsigned e = (unsigned)hs | ((unsigned)he << 8)
                       | ((unsigned)ws << 16) | ((unsigned)we << 24);
            t[gh * 7 + gw] = make_uint2(e, __float_as_uint(rcp));
        }
    }
}

// ---------- compact: stable per-batch ROI lists -----------------------------
__global__ __launch_bounds__(512) void compact_kernel(
    const float* __restrict__ rois, int R, int N,
    int* __restrict__ list, int* __restrict__ count)
{
    int wave = threadIdx.x >> 6, lane = threadIdx.x & 63;
    if (wave >= N) return;
    int b = wave, offset = 0;
    for (int r0 = 0; r0 < R; r0 += 64) {
        int r = r0 + lane;
        bool m = (r < R) && ((int)rois[(size_t)r * 5] == b);
        unsigned long long mask = __ballot(m);
        int pos = offset + __popcll(mask & ((1ull << lane) - 1ull));
        if (m) list[b * R + pos] = r;
        offset += __popcll(mask);
    }
    if (lane == 0) count[b] = offset;
}

// ---------- plane kernel: gll staging + 2-level II + O(1) bins --------------
__global__ __launch_bounds__(512) void psroi_plane_kernel(
    const float* __restrict__ feat, int R,
    const uint2* __restrict__ tab,
    const int* __restrict__ list, const int* __restrict__ count,
    float* __restrict__ dst)          // ws_T[c][r]
{
    __shared__ float ii[HH * IW];     // [80][84], cols 80..83 = junk pad
    __shared__ float tot[NSEG][HH];

    int tid = threadIdx.x;
    int bid = blockIdx.x;
    int b   = bid / CC;
    int c   = bid % CC;
    int rem = c % (GS * GS);          // gh*7+gw

    const float* plane = feat + ((size_t)b * CC + c) * PLANE;

    // ---- async stage: 1680 16B chunks, wave-uniform LDS base + lane*16 ----
    int wid = tid >> 6, lane = tid & 63;
    for (int q0 = wid * 64; q0 < NCHUNK; q0 += 512) {
        int q = q0 + lane;
        if (q < NCHUNK) {
            int row = q / 21;
            int c4  = q - row * 21;
            // pad chunk (c4==20): harmless dummy source, cols 80..83 never read
            const float* src = plane + row * WW + ((c4 < 20) ? c4 * 4 : 0);
            gll16(src, &ii[q0 * 4]);   // base uniform per wave; lane offset in HW
        }
    }
    __syncthreads();                   // drains vmcnt before first LDS read

    bool act = tid < NSEG * WW;
    int seg = tid / WW;                // 0..4
    int lw  = tid % WW;                // 0..79
    float v[SEGLEN];

    // ---- H cumsum (axis=2 first, as golden), conflict-free ----
    {
        int h0 = seg * SEGLEN;
        if (act) {
            float s = 0.0f;
            #pragma unroll
            for (int k = 0; k < SEGLEN; ++k) { v[k] = ii[(h0 + k) * IW + lw]; s += v[k]; }
            tot[seg][lw] = s;
        }
        __syncthreads();
        if (act) {
            float off = 0.0f;
            #pragma unroll
            for (int j = 0; j < NSEG - 1; ++j) if (j < seg) off += tot[j][lw];
            float run = off;
            #pragma unroll
            for (int k = 0; k < SEGLEN; ++k) { run += v[k]; ii[(h0 + k) * IW + lw] = run; }
        }
        __syncthreads();
    }
    // ---- W cumsum: float4 segments (16B aligned) ----
    {
        int w0 = seg * SEGLEN;
        if (act) {
            float4* rp = (float4*)&ii[lw * IW + w0];
            float s = 0.0f;
            #pragma unroll
            for (int k4 = 0; k4 < SEGLEN / 4; ++k4) {
                float4 f = rp[k4];
                v[k4*4+0] = f.x; v[k4*4+1] = f.y; v[k4*4+2] = f.z; v[k4*4+3] = f.w;
                s += f.x + f.y + f.z + f.w;
            }
            tot[seg][lw] = s;
        }
        __syncthreads();
        if (act) {
            float off = 0.0f;
            #pragma unroll
            for (int j = 0; j < NSEG - 1; ++j) if (j < seg) off += tot[j][lw];
            float run = off;
            #pragma unroll
            for (int k = 0; k < SEGLEN; ++k) { run += v[k]; v[k] = run; }
            float4* wp = (float4*)&ii[lw * IW + w0];
            #pragma unroll
            for (int k4 = 0; k4 < SEGLEN / 4; ++k4)
                wp[k4] = make_float4(v[k4*4+0], v[k4*4+1], v[k4*4+2], v[k4*4+3]);
        }
        __syncthreads();
    }

    // ---- ROI phase: one u64 table load + 4 guarded LDS reads + mul ----
    int cnt = count[b];
    const int* lst = list + b * R;
    for (int i = tid; i < cnt; i += 512) {
        int r = lst[i];
        uint2 t = tab[(size_t)r * 49 + rem];
        int hs =  t.x        & 255;
        int he = (t.x >> 8)  & 255;
        int ws = (t.x >> 16) & 255;
        int we = (t.x >> 24) & 255;
        float rcp = __uint_as_float(t.y);

        int h1 = max(he - 1, 0), h0i = max(hs - 1, 0);
        int w1 = max(we - 1, 0), w0i = max(ws - 1, 0);
        float vHEWE = ii[h1  * IW + w1];
        float vHSWE = ii[h0i * IW + w1];
        float vHEWS = ii[h1  * IW + w0i];
        float vHSWS = ii[h0i * IW + w0i];
        float A = (he > 0 && we > 0) ? vHEWE : 0.0f;
        float B = (hs > 0 && we > 0) ? vHSWE : 0.0f;
        float Cv = (he > 0 && ws > 0) ? vHEWS : 0.0f;
        float Dv = (hs > 0 && ws > 0) ? vHSWS : 0.0f;
        float s = ((A - B) - Cv) + Dv;    // golden's evaluation order
        dst[(size_t)c * R + r] = s * rcp;
    }
}

// ---------- fallback: correctness-only direct path (ws too small) -----------
__global__ __launch_bounds__(256) void psroi_fallback_kernel(
    const float* __restrict__ feat, const float* __restrict__ rois,
    int R, float* __restrict__ out)
{
    __shared__ float ii[81 * 81];
    int bid = blockIdx.x;
    int b = bid / CC, c = bid % CC;
    int rem = c % 49, gh = rem / 7, gw = rem % 7;

    const float* plane = feat + ((size_t)b * CC + c) * PLANE;
    for (int i = threadIdx.x; i < PLANE; i += 256) {
        int h = i / WW, w = i % WW;
        ii[(h + 1) * 81 + (w + 1)] = plane[i];
    }
    for (int i = threadIdx.x; i < 81; i += 256) { ii[i] = 0.0f; ii[i * 81] = 0.0f; }
    __syncthreads();
    if (threadIdx.x < WW) {
        int w = threadIdx.x + 1; float s = 0.0f;
        for (int h = 1; h <= HH; ++h) { s += ii[h * 81 + w]; ii[h * 81 + w] = s; }
    }
    __syncthreads();
    if (threadIdx.x < HH) {
        int h = threadIdx.x + 1; float* row = &ii[h * 81]; float s = 0.0f;
        for (int w = 1; w <= WW; ++w) { s += row[w]; row[w] = s; }
    }
    __syncthreads();
    for (int r = threadIdx.x; r < R; r += 256) {
        const float* roi = rois + (size_t)r * 5;
        if ((int)roi[0] != b) continue;
        float x1 = rintf(roi[1]) * 0.0625f;
        float y1 = rintf(roi[2]) * 0.0625f;
        float x2 = (rintf(roi[3]) + 1.0f) * 0.0625f;
        float y2 = (rintf(roi[4]) + 1.0f) * 0.0625f;
        float bw = fmaxf(x2 - x1, 0.1f) * recip7();
        float bh = fmaxf(y2 - y1, 0.1f) * recip7();
        asm volatile("" : "+v"(bw), "+v"(bh));
        int hs = (int)fminf(fmaxf(floorf(mul_add_nofma((float)gh,     bh, y1)), 0.0f), 80.0f);
        int he = (int)fminf(fmaxf(ceilf (mul_add_nofma((float)(gh+1), bh, y1)), 0.0f), 80.0f);
        int ws = (int)fminf(fmaxf(floorf(mul_add_nofma((float)gw,     bw, x1)), 0.0f), 80.0f);
        int we = (int)fminf(fmaxf(ceilf (mul_add_nofma((float)(gw+1), bw, x1)), 0.0f), 80.0f);
        float s = ii[he * 81 + we] - ii[hs * 81 + we] - ii[he * 81 + ws] + ii[hs * 81 + ws];
        int area = (he - hs) * (we - ws);
        out[(size_t)r * CC + c] = (area > 0) ? (s / (float)area) : 0.0f;
    }
}

// ---------- transpose: ws_T[1029][R] -> out[R][1029] ------------------------
__global__ __launch_bounds__(256) void transpose_kernel(
    const float* __restrict__ in, float* __restrict__ out, int R, int C)
{
    __shared__ float t[64][65];
    int r0 = blockIdx.x * 64;
    int c0 = blockIdx.y * 64;
    int tx = threadIdx.x, ty = threadIdx.y;

    #pragma unroll
    for (int k0 = 0; k0 < 64; k0 += 4) {
        int k = k0 + ty;
        int cc = c0 + k, rr = r0 + tx;
        if (cc < C && rr < R) t[k][tx] = in[(size_t)cc * R + rr];
    }
    __syncthreads();
    #pragma unroll
    for (int k0 = 0; k0 < 64; k0 += 4) {
        int k = k0 + ty;
        int rr = r0 + k, cc = c0 + tx;
        if (rr < R && cc < C) out[(size_t)rr * C + cc] = t[tx][k];
    }
}

extern "C" void kernel_launch(void* const* d_in, const int* in_sizes, int n_in,
                              void* d_out, int out_size, void* d_ws, size_t ws_size,
                              hipStream_t stream)
{
    const float* feat = (const float*)d_in[0];
    const float* rois = (const float*)d_in[1];
    float* out        = (float*)d_out;

    int R = in_sizes[1] / 5;
    int N = in_sizes[0] / (CC * PLANE);

    size_t off_wsT  = 0;
    size_t off_tab  = (off_wsT + (size_t)CC * R * sizeof(float) + 15) & ~(size_t)15;
    size_t off_list = (off_tab + (size_t)R * 49 * sizeof(uint2) + 15) & ~(size_t)15;
    size_t off_cnt  = off_list + (size_t)N * R * sizeof(int);
    size_t need     = off_cnt + (size_t)N * sizeof(int);

    if (ws_size >= need && N <= 8 && R <= 65536) {
        char* ws = (char*)d_ws;
        float* ws_T = (float*)(ws + off_wsT);
        uint2* tab  = (uint2*)(ws + off_tab);
        int*   list = (int*)(ws + off_list);
        int*   cnt  = (int*)(ws + off_cnt);

        edge_kernel<<<(R + 255) / 256, 256, 0, stream>>>(rois, R, tab);
        compact_kernel<<<1, 512, 0, stream>>>(rois, R, N, list, cnt);
        psroi_plane_kernel<<<N * CC, 512, 0, stream>>>(feat, R, tab, list, cnt, ws_T);
        dim3 blk(64, 4), grd((R + 63) / 64, (CC + 63) / 64);
        transpose_kernel<<<grd, blk, 0, stream>>>(ws_T, out, R, CC);
    } else {
        psroi_fallback_kernel<<<N * CC, 256, 0, stream>>>(feat, rois, R, out);
    }
}